// Round 19
// baseline (181.729 us; speedup 1.0000x reference)
//
#include <hip/hip_runtime.h>

#define NN 50000
#define NE 800000
#define NG 256
#define NBUK 196            // ceil(NN/256) — 256-node buckets
#define EPB 3125            // edges per block (256*3125 == 800000 exactly)
#define NBLK 256
#define PSLICE 8            // pool slices per graph

// ================= bf16 helpers (packed 2 per uint) =================

__device__ __forceinline__ float bflo(unsigned u) { return __uint_as_float(u << 16); }
__device__ __forceinline__ float bfhi(unsigned u) { return __uint_as_float(u & 0xFFFF0000u); }
__device__ __forceinline__ unsigned bfr_hi(float x) {          // RNE bf16, kept in high bits
    unsigned u = __float_as_uint(x);
    return (u + 0x7FFFu + ((u >> 16) & 1u)) & 0xFFFF0000u;
}
__device__ __forceinline__ unsigned bfpack2(float x, float y) {
    unsigned ux = __float_as_uint(x), uy = __float_as_uint(y);
    unsigned lx = (ux + 0x7FFFu + ((ux >> 16) & 1u)) >> 16;
    unsigned hy = (uy + 0x7FFFu + ((uy >> 16) & 1u)) & 0xFFFF0000u;
    return lx | hy;
}
__device__ __forceinline__ void bfacc8(float* A, float c, uint4 v) {
    A[0] += c * bflo(v.x); A[1] += c * bfhi(v.x);
    A[2] += c * bflo(v.y); A[3] += c * bfhi(v.y);
    A[4] += c * bflo(v.z); A[5] += c * bfhi(v.z);
    A[6] += c * bflo(v.w); A[7] += c * bfhi(v.w);
}

// ========== fat kernel 1: kA1 histogram (blocks 0..NBLK-1) ∥ layer-1 GEMM ==========

__global__ __launch_bounds__(256) void k_fat1(const int* __restrict__ dst,
                                              int* __restrict__ pbb,
                                              const float* __restrict__ x,
                                              const float* __restrict__ W,
                                              unsigned* __restrict__ xwout, int n) {
    __shared__ int hist[NBUK];
    __shared__ float  hT[64 * 68];
    __shared__ float4 Wl[64 * 4];

    int tid = threadIdx.x;
    if (blockIdx.x < NBLK) {
        for (int k = tid; k < NBUK; k += 256) hist[k] = 0;
        __syncthreads();
        int b = blockIdx.x;
        int e0 = b * EPB, e1 = min(NE, e0 + EPB);
        for (int i = e0 + tid; i < e1; i += 256)
            atomicAdd(&hist[dst[i] >> 8], 1);
        __syncthreads();
        for (int k = tid; k < NBUK; k += 256)
            pbb[b * NBUK + k] = hist[k];
        return;
    }
    constexpr int FIN = 64, FOUT = 16;
    constexpr int TC = FOUT / 4;      // 4
    constexpr int TR = 256 / TC;      // 64
    constexpr int R  = 64 / TR;       // 1
    constexpr int SA = 68;
    constexpr int CB = FIN / 4;       // 16

    int rowbase = (blockIdx.x - NBLK) * 64;

    for (int i = tid; i < FIN * TC; i += 256) Wl[i] = ((const float4*)W)[i];

    for (int blk = tid; blk < 16 * CB; blk += 256) {
        int br = blk / CB, bc = blk % CB;
        float4 v[4];
        #pragma unroll
        for (int i = 0; i < 4; ++i) {
            int rr = rowbase + 4 * br + i;
            if (rr >= n) rr = n - 1;
            v[i] = *(const float4*)(x + (long long)rr * FIN + 4 * bc);
        }
        #pragma unroll
        for (int j = 0; j < 4; ++j) {
            float4 t;
            t.x = ((float*)&v[0])[j];
            t.y = ((float*)&v[1])[j];
            t.z = ((float*)&v[2])[j];
            t.w = ((float*)&v[3])[j];
            *(float4*)&hT[(4 * bc + j) * SA + 4 * br] = t;
        }
    }
    __syncthreads();

    int tc = tid % TC;
    int r0 = (tid / TC) * R;

    float4 acc = make_float4(0.f, 0.f, 0.f, 0.f);
    #pragma unroll 4
    for (int fi = 0; fi < FIN; ++fi) {
        float4 wv = Wl[fi * TC + tc];
        float a = hT[fi * SA + r0];
        acc.x += a * wv.x; acc.y += a * wv.y;
        acc.z += a * wv.z; acc.w += a * wv.w;
    }

    int row = rowbase + r0;
    if (row < n) {
        uint2 o;
        o.x = bfpack2(acc.x, acc.y); o.y = bfpack2(acc.z, acc.w);
        ((uint2*)xwout)[(long long)row * (FOUT / 4) + tc] = o;
    }
}

// parallel per-bucket scan: one 64-lane wave per bucket over NBLK block counts
__global__ __launch_bounds__(256) void k_pbbscan(int* __restrict__ pbb,
                                                 int* __restrict__ bucketCnt) {
    int k = blockIdx.x * 4 + (threadIdx.x >> 6);
    int lane = threadIdx.x & 63;
    if (k >= NBUK) return;
    int run = 0;
    for (int base = 0; base < NBLK; base += 64) {
        int b = base + lane;
        int v = pbb[b * NBUK + k];
        int inc = v;
        for (int off = 1; off < 64; off *= 2) {
            int u = __shfl_up(inc, off);
            if (lane >= off) inc += u;
        }
        pbb[b * NBUK + k] = inc - v + run;
        run += __shfl(inc, 63);
    }
    if (lane == 0) bucketCnt[k] = run;
}

// scan 196 bucket totals -> exclusive bucketBase
__global__ __launch_bounds__(256) void k_bscan(const int* __restrict__ bucketCnt,
                                               int* __restrict__ bucketBase,
                                               int* __restrict__ rowptr) {
    int t = threadIdx.x;
    int v = (t < NBUK) ? bucketCnt[t] : 0;
    __shared__ int wsum[4];
    int inc = v;
    for (int off = 1; off < 64; off *= 2) {
        int u = __shfl_up(inc, off);
        if ((t & 63) >= off) inc += u;
    }
    if ((t & 63) == 63) wsum[t >> 6] = inc;
    __syncthreads();
    if (t == 0) { int s = 0; for (int i = 0; i < 4; ++i) { int x = wsum[i]; wsum[i] = s; s += x; } }
    __syncthreads();
    int ex = inc - v + wsum[t >> 6];
    if (t < NBUK) bucketBase[t] = ex;
    if (t == 0) { bucketBase[NBUK] = NE; rowptr[NN] = NE; }
}

// pass A2: scatter packed edges into bucket ranges (coalesced pbb load, LDS cursors)
__global__ __launch_bounds__(256) void kA2(const int* __restrict__ src,
                                           const int* __restrict__ dst,
                                           const float* __restrict__ w,
                                           const int* __restrict__ bucketBase,
                                           const int* __restrict__ pbb,
                                           int2* __restrict__ tmp) {
    __shared__ int cur[NBUK];
    __shared__ int base[NBUK];
    int b = blockIdx.x;
    for (int k = threadIdx.x; k < NBUK; k += 256) {
        base[k] = bucketBase[k] + pbb[b * NBUK + k];
        cur[k] = 0;
    }
    __syncthreads();
    int e0 = b * EPB, e1 = min(NE, e0 + EPB);
    for (int i = e0 + threadIdx.x; i < e1; i += 256) {
        int d = dst[i];
        int k = d >> 8;
        int pos = base[k] + atomicAdd(&cur[k], 1);
        tmp[pos] = make_int2(((d & 255) << 16) | src[i], __float_as_int(w[i]));
    }
}

// pass B: one block per 256-node bucket -> counting sort, rowptr, dinv/selfc
__global__ __launch_bounds__(256) void kB(const int2* __restrict__ tmp,
                                          const int* __restrict__ bucketBase,
                                          int* __restrict__ rowptr,
                                          float* __restrict__ dinv,
                                          float* __restrict__ selfc,
                                          unsigned* __restrict__ sedge) {
    __shared__ int   cnt[256];
    __shared__ float degs[256];
    __shared__ int   curs[256];
    __shared__ int   wsum[4];
    int b = blockIdx.x;
    int tid = threadIdx.x;
    cnt[tid] = 0; degs[tid] = 0.f;
    __syncthreads();
    int s0 = bucketBase[b], s1 = bucketBase[b + 1];
    for (int p = s0 + tid; p < s1; p += 256) {
        int2 e = tmp[p];
        int n8 = e.x >> 16;
        atomicAdd(&cnt[n8], 1);
        atomicAdd(&degs[n8], __int_as_float(e.y));
    }
    __syncthreads();
    int c = cnt[tid];
    int inc = c;
    for (int off = 1; off < 64; off *= 2) {
        int u = __shfl_up(inc, off);
        if ((tid & 63) >= off) inc += u;
    }
    if ((tid & 63) == 63) wsum[tid >> 6] = inc;
    __syncthreads();
    if (tid == 0) { int s = 0; for (int i = 0; i < 4; ++i) { int x = wsum[i]; wsum[i] = s; s += x; } }
    __syncthreads();
    int ex = inc - c + wsum[tid >> 6];
    curs[tid] = ex;
    int node = b * 256 + tid;
    if (node < NN) {
        rowptr[node] = s0 + ex;
        float deg = 1.0f + degs[tid];
        float r = rsqrtf(deg);
        dinv[node] = r;
        selfc[node] = r * r;
    }
    __syncthreads();
    for (int p = s0 + tid; p < s1; p += 256) {
        int2 e = tmp[p];
        int n8 = e.x >> 16;
        int pos = s0 + atomicAdd(&curs[n8], 1);
        sedge[pos] = (unsigned)(e.x & 0xFFFF) | bfr_hi(__int_as_float(e.y));
    }
}

// stored w(bf16,hi) -> coef = dinv[src]*w*dinv[dst] (bf16,hi); src kept in low 16
__global__ void k_coef(const int* __restrict__ rowptr, const float* __restrict__ dinv,
                       unsigned* __restrict__ sedge) {
    int r = blockIdx.x * blockDim.x + threadIdx.x;
    if (r >= NN) return;
    int e0 = rowptr[r], e1 = rowptr[r + 1];
    float dr = dinv[r];
    for (int p = e0; p < e1; ++p) {
        unsigned u = sedge[p];
        float c = dinv[u & 0xFFFFu] * bfhi(u) * dr;
        sedge[p] = (u & 0xFFFFu) | bfr_hi(c);
    }
}

// ====== bf16 edge-gather: acc[8] += coef * h_bf16[src][lane*8 .. +7] ======

template<int G>
__device__ __forceinline__ void agg_row_bf(const uint4* __restrict__ h4,
                                           const unsigned* __restrict__ se,
                                           int lane, int e0, int e1, float* acc) {
    float b0[8], b1[8], b2[8];
    #pragma unroll
    for (int j = 0; j < 8; ++j) { b0[j] = 0.f; b1[j] = 0.f; b2[j] = 0.f; }
    int p = e0;
    for (; p + 4 <= e1; p += 4) {
        unsigned u0 = se[p], u1 = se[p + 1], u2 = se[p + 2], u3 = se[p + 3];
        uint4 v0 = h4[(long long)(u0 & 0xFFFFu) * G + lane];
        uint4 v1 = h4[(long long)(u1 & 0xFFFFu) * G + lane];
        uint4 v2 = h4[(long long)(u2 & 0xFFFFu) * G + lane];
        uint4 v3 = h4[(long long)(u3 & 0xFFFFu) * G + lane];
        bfacc8(acc, bfhi(u0), v0);
        bfacc8(b0,  bfhi(u1), v1);
        bfacc8(b1,  bfhi(u2), v2);
        bfacc8(b2,  bfhi(u3), v3);
    }
    for (; p < e1; ++p) {
        unsigned u = se[p];
        uint4 v = h4[(long long)(u & 0xFFFFu) * G + lane];
        bfacc8(acc, bfhi(u), v);
    }
    #pragma unroll
    for (int j = 0; j < 8; ++j) acc[j] += (b0[j] + b1[j]) + b2[j];
}

// ====== standalone aggregation (layer 1, bf16 h): out = agg(h)+bias,relu ======
// Degree-sorted row assignment: block ranking-sorts its NPB rows by length so
// lane-groups within a wave get near-equal rows (kills divergence idle).

template<int F, bool BRELU>
__global__ __launch_bounds__(256) void k_agg_bf(const unsigned* __restrict__ h,
                         const int* __restrict__ rowptr,
                         const unsigned* __restrict__ se, const float* __restrict__ selfc,
                         const float* __restrict__ bias, unsigned* __restrict__ out, int n) {
    constexpr int G = F / 8;             // uint4 (8 bf16) per row
    constexpr int NPB = 256 / G;
    __shared__ int degl[NPB];
    __shared__ int perm[NPB];
    int tid = threadIdx.x;
    int rowbase = blockIdx.x * NPB;
    if (tid < NPB) {
        int gid = rowbase + tid;
        int gidc = (gid < n) ? gid : (n - 1);
        degl[tid] = rowptr[gidc + 1] - rowptr[gidc];
    }
    __syncthreads();
    if (tid < NPB) {
        int d = degl[tid];
        int rank = 0;
        for (int j = 0; j < NPB; ++j) {
            int dj = degl[j];
            rank += (dj < d) || (dj == d && j < tid);
        }
        perm[rank] = tid;
    }
    __syncthreads();

    int sub = tid / G;
    int lane = tid & (G - 1);
    int lrow = perm[sub];
    int gid = rowbase + lrow;
    if (gid >= n) return;
    const uint4* h4 = (const uint4*)h;
    float acc[8];
    #pragma unroll
    for (int j = 0; j < 8; ++j) acc[j] = 0.f;
    uint4 sv = h4[(long long)gid * G + lane];
    bfacc8(acc, selfc[gid], sv);
    agg_row_bf<G>(h4, se, lane, rowptr[gid], rowptr[gid + 1], acc);
    if (BRELU) {
        float4 bv0 = ((const float4*)bias)[lane * 2];
        float4 bv1 = ((const float4*)bias)[lane * 2 + 1];
        acc[0] = fmaxf(acc[0] + bv0.x, 0.f); acc[1] = fmaxf(acc[1] + bv0.y, 0.f);
        acc[2] = fmaxf(acc[2] + bv0.z, 0.f); acc[3] = fmaxf(acc[3] + bv0.w, 0.f);
        acc[4] = fmaxf(acc[4] + bv1.x, 0.f); acc[5] = fmaxf(acc[5] + bv1.y, 0.f);
        acc[6] = fmaxf(acc[6] + bv1.z, 0.f); acc[7] = fmaxf(acc[7] + bv1.w, 0.f);
    }
    uint4 o;
    o.x = bfpack2(acc[0], acc[1]); o.y = bfpack2(acc[2], acc[3]);
    o.z = bfpack2(acc[4], acc[5]); o.w = bfpack2(acc[6], acc[7]);
    ((uint4*)out)[(long long)gid * G + lane] = o;
}

// ====== fused aggregate + dense (bf16 h in / bf16 out, fp32 compute) ======
// Degree-sorted row assignment in the aggregate phase (perm); GEMM unchanged.

template<int FAGG, int FOUT, int ROWS, bool RELU>
__global__ __launch_bounds__(256) void k_aggemm_bf(const unsigned* __restrict__ h,
                                                   const int* __restrict__ rowptr,
                                                   const unsigned* __restrict__ se,
                                                   const float* __restrict__ selfc,
                                                   const float* __restrict__ W,
                                                   const float* __restrict__ b,
                                                   unsigned* __restrict__ out, int n) {
    constexpr int G    = FAGG / 8;    // uint4 lanes per node
    constexpr int NPP  = 256 / G;     // nodes per agg pass
    constexpr int PASS = ROWS / NPP;
    constexpr int SA   = ROWS + 4;    // LDS row stride
    constexpr int TC   = FOUT / 4;    // thread-cols in gemm phase
    constexpr int TR   = 256 / TC;
    constexpr int R    = ROWS / TR;   // rows per thread

    __shared__ float  hT[FAGG * SA];
    __shared__ float4 bl[TC];
    __shared__ int    degl[ROWS];
    __shared__ int    perm[ROWS];

    int tid = threadIdx.x;
    int rowbase = blockIdx.x * ROWS;
    const float4* Wf4 = (const float4*)W;

    if (tid < TC) bl[tid] = ((const float4*)b)[tid];

    // ---- phase 0: degree-sorted permutation of the block's rows ----
    if (tid < ROWS) {
        int gid = rowbase + tid;
        int gidc = (gid < n) ? gid : (n - 1);
        degl[tid] = rowptr[gidc + 1] - rowptr[gidc];
    }
    __syncthreads();
    if (tid < ROWS) {
        int d = degl[tid];
        int rank = 0;
        for (int j = 0; j < ROWS; ++j) {
            int dj = degl[j];
            rank += (dj < d) || (dj == d && j < tid);
        }
        perm[rank] = tid;
    }
    __syncthreads();

    // ---- phase 1: aggregate ROWS rows into hT (transposed, fp32) ----
    const uint4* h4 = (const uint4*)h;
    int lane = tid & (G - 1);
    int sub  = tid / G;
    #pragma unroll
    for (int ps = 0; ps < PASS; ++ps) {
        int lrow = perm[ps * NPP + sub];
        int gid = rowbase + lrow;
        int gidc = (gid < n) ? gid : (n - 1);
        float acc[8];
        #pragma unroll
        for (int j = 0; j < 8; ++j) acc[j] = 0.f;
        uint4 sv = h4[(long long)gidc * G + lane];
        bfacc8(acc, selfc[gidc], sv);
        agg_row_bf<G>(h4, se, lane, rowptr[gidc], rowptr[gidc + 1], acc);
        #pragma unroll
        for (int j = 0; j < 8; ++j)
            hT[(8 * lane + j) * SA + lrow] = acc[j];
    }
    __syncthreads();

    // ---- phase 2: gemm (fp32 from LDS, W from global L1/L2) ----
    int tc = tid % TC;
    int r0 = (tid / TC) * R;

    float4 acc[R];
    float4 binit = bl[tc];
    #pragma unroll
    for (int r = 0; r < R; ++r) acc[r] = binit;

    #pragma unroll 4
    for (int fi = 0; fi < FAGG; ++fi) {
        float4 wv = __ldg(&Wf4[fi * TC + tc]);
        float a[R];
        if constexpr (R >= 4) {
            #pragma unroll
            for (int rb = 0; rb < R / 4; ++rb) {
                float4 t = *(const float4*)&hT[fi * SA + r0 + 4 * rb];
                a[4 * rb + 0] = t.x; a[4 * rb + 1] = t.y;
                a[4 * rb + 2] = t.z; a[4 * rb + 3] = t.w;
            }
        } else if constexpr (R == 2) {
            float2 t = *(const float2*)&hT[fi * SA + r0];
            a[0] = t.x; a[1] = t.y;
        } else {
            a[0] = hT[fi * SA + r0];
        }
        #pragma unroll
        for (int r = 0; r < R; ++r) {
            acc[r].x += a[r] * wv.x; acc[r].y += a[r] * wv.y;
            acc[r].z += a[r] * wv.z; acc[r].w += a[r] * wv.w;
        }
    }

    #pragma unroll
    for (int r = 0; r < R; ++r) {
        int row = rowbase + r0 + r;
        if (row < n) {
            float4 v = acc[r];
            if (RELU) {
                v.x = fmaxf(v.x, 0.f); v.y = fmaxf(v.y, 0.f);
                v.z = fmaxf(v.z, 0.f); v.w = fmaxf(v.w, 0.f);
            }
            uint2 o;
            o.x = bfpack2(v.x, v.y); o.y = bfpack2(v.z, v.w);
            ((uint2*)out)[(long long)row * (FOUT / 4) + tc] = o;
        }
    }
}

// ============ global add pool + relu (two-phase, bf16 h, batch sorted) ============

__global__ __launch_bounds__(64) void k_pool1(const unsigned* __restrict__ h,
                                              const int* __restrict__ batch,
                                              float* __restrict__ part, int n) {
    int g = blockIdx.x / PSLICE;
    int s = blockIdx.x % PSLICE;
    int lo = 0, hi = n;
    while (lo < hi) { int m = (lo + hi) >> 1; if (batch[m] < g) lo = m + 1; else hi = m; }
    int start = lo;
    hi = n;
    while (lo < hi) { int m = (lo + hi) >> 1; if (batch[m] < g + 1) lo = m + 1; else hi = m; }
    int end = lo;
    int len = end - start;
    int a = start + (int)((long long)len * s / PSLICE);
    int bnd = start + (int)((long long)len * (s + 1) / PSLICE);
    int t = threadIdx.x;                 // covers features 2t, 2t+1 (row = 64 uints)
    float a0 = 0.f, a1 = 0.f, b0 = 0.f, b1 = 0.f;
    int i = a;
    for (; i + 2 <= bnd; i += 2) {
        unsigned u0 = h[(long long)(i + 0) * 64 + t];
        unsigned u1 = h[(long long)(i + 1) * 64 + t];
        a0 += bflo(u0); a1 += bfhi(u0);
        b0 += bflo(u1); b1 += bfhi(u1);
    }
    if (i < bnd) {
        unsigned u0 = h[(long long)i * 64 + t];
        a0 += bflo(u0); a1 += bfhi(u0);
    }
    part[(long long)blockIdx.x * 128 + 2 * t]     = a0 + b0;
    part[(long long)blockIdx.x * 128 + 2 * t + 1] = a1 + b1;
}

__global__ __launch_bounds__(128) void k_pool2(const float* __restrict__ part,
                                               float* __restrict__ out) {
    int g = blockIdx.x;
    int f = threadIdx.x;
    float acc = 0.f;
    #pragma unroll
    for (int s = 0; s < PSLICE; ++s)
        acc += part[(long long)(g * PSLICE + s) * 128 + f];
    out[g * 128 + f] = fmaxf(acc, 0.0f);
}

// ================= launch =================

static inline int cdiv(long long a, int b) { return (int)((a + b - 1) / b); }

extern "C" void kernel_launch(void* const* d_in, const int* in_sizes, int n_in,
                              void* d_out, int out_size, void* d_ws, size_t ws_size,
                              hipStream_t stream) {
    const float* x    = (const float*)d_in[0];
    const int*   src  = (const int*)d_in[1];
    const int*   dst  = src + NE;
    const float* ew   = (const float*)d_in[2];
    const int*   batch= (const int*)d_in[3];
    const float* W1 = (const float*)d_in[4];  const float* b1 = (const float*)d_in[5];
    const float* W2 = (const float*)d_in[6];  const float* b2 = (const float*)d_in[7];
    const float* W3 = (const float*)d_in[8];  const float* b3 = (const float*)d_in[9];
    const float* W4 = (const float*)d_in[10]; const float* b4 = (const float*)d_in[11];
    const float* W5 = (const float*)d_in[12]; const float* b5 = (const float*)d_in[13];
    float* out = (float*)d_out;

    // ---- workspace layout (floats) ----
    float* ws = (float*)d_ws;
    int*      rowptr = (int*)ws;                       // [50004] ints
    unsigned* sedge  = (unsigned*)(ws + 50004);        // [NE] uints (region reserves 2*NE)
    float*    selfc  = ws + 50004 + 2 * (size_t)NE;    // [NN]
    float*    dinv   = selfc + NN;                     // [NN]
    float*    bufA   = dinv + NN;                      // [NN*64] floats
    float*    bufB   = bufA + (size_t)NN * 64;         // [NN*128] floats
    unsigned* hA  = (unsigned*)bufA;                   // bf16 h buffers
    unsigned* hB  = (unsigned*)bufB;
    int2*     tmp = (int2*)bufB;                       // NE int2 (dead before hB written)
    int*   pbb        = (int*)(bufB + (size_t)NN * 128);   // NBLK*NBUK ints
    int*   bucketCnt  = pbb + NBLK * NBUK;                 // NBUK
    int*   bucketBase = bucketCnt + NBUK;                  // NBUK+1
    float* part       = (float*)(bucketBase + NBUK + 1);   // NG*PSLICE*128 fp32

    const int T = 256;

    // ---- fat kernel: kA1 histogram ∥ layer-1 GEMM (independent) ----
    k_fat1<<<NBLK + cdiv(NN, 64), T, 0, stream>>>(dst, pbb, x, W1, hA, NN);

    // ---- CSR build (coalesced, parallel atomic-free offsets) ----
    k_pbbscan<<<cdiv(NBUK, 4), T, 0, stream>>>(pbb, bucketCnt);
    k_bscan<<<1, T, 0, stream>>>(bucketCnt, bucketBase, rowptr);
    kA2<<<NBLK, T, 0, stream>>>(src, dst, ew, bucketBase, pbb, tmp);
    kB<<<NBUK, T, 0, stream>>>(tmp, bucketBase, rowptr, dinv, selfc, sedge);
    k_coef<<<cdiv(NN, T), T, 0, stream>>>(rowptr, dinv, sedge);

    // ---- layer 1 aggregate (+bias+relu) ----
    k_agg_bf<16, true><<<cdiv(NN, 128), T, 0, stream>>>(hA, rowptr, sedge, selfc, b1, hB, NN);

    // ---- layers 2-5: fused aggregate + dense (bf16 h, fp32 compute) ----
    k_aggemm_bf<16, 32, 128, true ><<<cdiv(NN, 128), T, 0, stream>>>(hB, rowptr, sedge, selfc, W2, b2, hA, NN);
    k_aggemm_bf<32, 64,  64, true ><<<cdiv(NN, 64),  T, 0, stream>>>(hA, rowptr, sedge, selfc, W3, b3, hB, NN);
    k_aggemm_bf<64, 64,  64, true ><<<cdiv(NN, 64),  T, 0, stream>>>(hB, rowptr, sedge, selfc, W4, b4, hA, NN);
    k_aggemm_bf<64, 128, 64, false><<<cdiv(NN, 64),  T, 0, stream>>>(hA, rowptr, sedge, selfc, W5, b5, hB, NN);

    // ---- global add pool + relu (two-phase) ----
    k_pool1<<<NG * PSLICE, 64, 0, stream>>>(hB, batch, part, NN);
    k_pool2<<<NG, 128, 0, stream>>>(part, out);
}

// Round 20
// 170.805 us; speedup vs baseline: 1.0640x; 1.0640x over previous
//
#include <hip/hip_runtime.h>

#define NN 50000
#define NE 800000
#define NG 256
#define NBUK 196            // ceil(NN/256) — 256-node buckets
#define EPB 3125            // edges per block (256*3125 == 800000 exactly)
#define NBLK 256
#define PSLICE 8            // pool slices per graph

// ================= bf16 helpers (packed 2 per uint) =================

__device__ __forceinline__ float bflo(unsigned u) { return __uint_as_float(u << 16); }
__device__ __forceinline__ float bfhi(unsigned u) { return __uint_as_float(u & 0xFFFF0000u); }
__device__ __forceinline__ unsigned bfr_hi(float x) {          // RNE bf16, kept in high bits
    unsigned u = __float_as_uint(x);
    return (u + 0x7FFFu + ((u >> 16) & 1u)) & 0xFFFF0000u;
}
__device__ __forceinline__ unsigned bfpack2(float x, float y) {
    unsigned ux = __float_as_uint(x), uy = __float_as_uint(y);
    unsigned lx = (ux + 0x7FFFu + ((ux >> 16) & 1u)) >> 16;
    unsigned hy = (uy + 0x7FFFu + ((uy >> 16) & 1u)) & 0xFFFF0000u;
    return lx | hy;
}
__device__ __forceinline__ void bfacc8(float* A, float c, uint4 v) {
    A[0] += c * bflo(v.x); A[1] += c * bfhi(v.x);
    A[2] += c * bflo(v.y); A[3] += c * bfhi(v.y);
    A[4] += c * bflo(v.z); A[5] += c * bfhi(v.z);
    A[6] += c * bflo(v.w); A[7] += c * bfhi(v.w);
}

// ========== fat kernel 1: kA1 histogram (blocks 0..NBLK-1) ∥ layer-1 GEMM ==========

__global__ __launch_bounds__(256) void k_fat1(const int* __restrict__ dst,
                                              int* __restrict__ pbb,
                                              const float* __restrict__ x,
                                              const float* __restrict__ W,
                                              unsigned* __restrict__ xwout, int n) {
    __shared__ int hist[NBUK];
    __shared__ float  hT[64 * 68];
    __shared__ float4 Wl[64 * 4];

    int tid = threadIdx.x;
    if (blockIdx.x < NBLK) {
        // ---- kA1 body ----
        for (int k = tid; k < NBUK; k += 256) hist[k] = 0;
        __syncthreads();
        int b = blockIdx.x;
        int e0 = b * EPB, e1 = min(NE, e0 + EPB);
        for (int i = e0 + tid; i < e1; i += 256)
            atomicAdd(&hist[dst[i] >> 8], 1);
        __syncthreads();
        for (int k = tid; k < NBUK; k += 256)
            pbb[b * NBUK + k] = hist[k];
        return;
    }
    // ---- layer-1 GEMM body: FIN=64, FOUT=16 ----
    constexpr int FIN = 64, FOUT = 16;
    constexpr int TC = FOUT / 4;      // 4
    constexpr int TR = 256 / TC;      // 64
    constexpr int R  = 64 / TR;       // 1
    constexpr int SA = 68;
    constexpr int CB = FIN / 4;       // 16

    int rowbase = (blockIdx.x - NBLK) * 64;

    for (int i = tid; i < FIN * TC; i += 256) Wl[i] = ((const float4*)W)[i];

    for (int blk = tid; blk < 16 * CB; blk += 256) {
        int br = blk / CB, bc = blk % CB;
        float4 v[4];
        #pragma unroll
        for (int i = 0; i < 4; ++i) {
            int rr = rowbase + 4 * br + i;
            if (rr >= n) rr = n - 1;
            v[i] = *(const float4*)(x + (long long)rr * FIN + 4 * bc);
        }
        #pragma unroll
        for (int j = 0; j < 4; ++j) {
            float4 t;
            t.x = ((float*)&v[0])[j];
            t.y = ((float*)&v[1])[j];
            t.z = ((float*)&v[2])[j];
            t.w = ((float*)&v[3])[j];
            *(float4*)&hT[(4 * bc + j) * SA + 4 * br] = t;
        }
    }
    __syncthreads();

    int tc = tid % TC;
    int r0 = (tid / TC) * R;

    float4 acc = make_float4(0.f, 0.f, 0.f, 0.f);
    #pragma unroll 4
    for (int fi = 0; fi < FIN; ++fi) {
        float4 wv = Wl[fi * TC + tc];
        float a = hT[fi * SA + r0];
        acc.x += a * wv.x; acc.y += a * wv.y;
        acc.z += a * wv.z; acc.w += a * wv.w;
    }

    int row = rowbase + r0;
    if (row < n) {
        uint2 o;
        o.x = bfpack2(acc.x, acc.y); o.y = bfpack2(acc.z, acc.w);
        ((uint2*)xwout)[(long long)row * (FOUT / 4) + tc] = o;
    }
}

// parallel per-bucket scan: one 64-lane wave per bucket over NBLK block counts
__global__ __launch_bounds__(256) void k_pbbscan(int* __restrict__ pbb,
                                                 int* __restrict__ bucketCnt) {
    int k = blockIdx.x * 4 + (threadIdx.x >> 6);
    int lane = threadIdx.x & 63;
    if (k >= NBUK) return;
    int run = 0;
    for (int base = 0; base < NBLK; base += 64) {
        int b = base + lane;
        int v = pbb[b * NBUK + k];
        int inc = v;
        for (int off = 1; off < 64; off *= 2) {
            int u = __shfl_up(inc, off);
            if (lane >= off) inc += u;
        }
        pbb[b * NBUK + k] = inc - v + run;
        run += __shfl(inc, 63);
    }
    if (lane == 0) bucketCnt[k] = run;
}

// scan 196 bucket totals -> exclusive bucketBase
__global__ __launch_bounds__(256) void k_bscan(const int* __restrict__ bucketCnt,
                                               int* __restrict__ bucketBase,
                                               int* __restrict__ rowptr) {
    int t = threadIdx.x;
    int v = (t < NBUK) ? bucketCnt[t] : 0;
    __shared__ int wsum[4];
    int inc = v;
    for (int off = 1; off < 64; off *= 2) {
        int u = __shfl_up(inc, off);
        if ((t & 63) >= off) inc += u;
    }
    if ((t & 63) == 63) wsum[t >> 6] = inc;
    __syncthreads();
    if (t == 0) { int s = 0; for (int i = 0; i < 4; ++i) { int x = wsum[i]; wsum[i] = s; s += x; } }
    __syncthreads();
    int ex = inc - v + wsum[t >> 6];
    if (t < NBUK) bucketBase[t] = ex;
    if (t == 0) { bucketBase[NBUK] = NE; rowptr[NN] = NE; }
}

// pass A2: scatter packed edges into bucket ranges (coalesced pbb load, LDS cursors)
__global__ __launch_bounds__(256) void kA2(const int* __restrict__ src,
                                           const int* __restrict__ dst,
                                           const float* __restrict__ w,
                                           const int* __restrict__ bucketBase,
                                           const int* __restrict__ pbb,
                                           int2* __restrict__ tmp) {
    __shared__ int cur[NBUK];
    __shared__ int base[NBUK];
    int b = blockIdx.x;
    for (int k = threadIdx.x; k < NBUK; k += 256) {
        base[k] = bucketBase[k] + pbb[b * NBUK + k];
        cur[k] = 0;
    }
    __syncthreads();
    int e0 = b * EPB, e1 = min(NE, e0 + EPB);
    for (int i = e0 + threadIdx.x; i < e1; i += 256) {
        int d = dst[i];
        int k = d >> 8;
        int pos = base[k] + atomicAdd(&cur[k], 1);
        tmp[pos] = make_int2(((d & 255) << 16) | src[i], __float_as_int(w[i]));
    }
}

// pass B: one block per 256-node bucket -> counting sort, rowptr, dinv/selfc
__global__ __launch_bounds__(256) void kB(const int2* __restrict__ tmp,
                                          const int* __restrict__ bucketBase,
                                          int* __restrict__ rowptr,
                                          float* __restrict__ dinv,
                                          float* __restrict__ selfc,
                                          unsigned* __restrict__ sedge) {
    __shared__ int   cnt[256];
    __shared__ float degs[256];
    __shared__ int   curs[256];
    __shared__ int   wsum[4];
    int b = blockIdx.x;
    int tid = threadIdx.x;
    cnt[tid] = 0; degs[tid] = 0.f;
    __syncthreads();
    int s0 = bucketBase[b], s1 = bucketBase[b + 1];
    for (int p = s0 + tid; p < s1; p += 256) {
        int2 e = tmp[p];
        int n8 = e.x >> 16;
        atomicAdd(&cnt[n8], 1);
        atomicAdd(&degs[n8], __int_as_float(e.y));
    }
    __syncthreads();
    int c = cnt[tid];
    int inc = c;
    for (int off = 1; off < 64; off *= 2) {
        int u = __shfl_up(inc, off);
        if ((tid & 63) >= off) inc += u;
    }
    if ((tid & 63) == 63) wsum[tid >> 6] = inc;
    __syncthreads();
    if (tid == 0) { int s = 0; for (int i = 0; i < 4; ++i) { int x = wsum[i]; wsum[i] = s; s += x; } }
    __syncthreads();
    int ex = inc - c + wsum[tid >> 6];
    curs[tid] = ex;
    int node = b * 256 + tid;
    if (node < NN) {
        rowptr[node] = s0 + ex;
        float deg = 1.0f + degs[tid];
        float r = rsqrtf(deg);
        dinv[node] = r;
        selfc[node] = r * r;
    }
    __syncthreads();
    for (int p = s0 + tid; p < s1; p += 256) {
        int2 e = tmp[p];
        int n8 = e.x >> 16;
        int pos = s0 + atomicAdd(&curs[n8], 1);
        sedge[pos] = (unsigned)(e.x & 0xFFFF) | bfr_hi(__int_as_float(e.y));
    }
}

// stored w(bf16,hi) -> coef = dinv[src]*w*dinv[dst] (bf16,hi); src kept in low 16
__global__ void k_coef(const int* __restrict__ rowptr, const float* __restrict__ dinv,
                       unsigned* __restrict__ sedge) {
    int r = blockIdx.x * blockDim.x + threadIdx.x;
    if (r >= NN) return;
    int e0 = rowptr[r], e1 = rowptr[r + 1];
    float dr = dinv[r];
    for (int p = e0; p < e1; ++p) {
        unsigned u = sedge[p];
        float c = dinv[u & 0xFFFFu] * bfhi(u) * dr;
        sedge[p] = (u & 0xFFFFu) | bfr_hi(c);
    }
}

// ====== bf16 edge-gather: acc[8] += coef * h_bf16[src][lane*8 .. +7] ======

template<int G>
__device__ __forceinline__ void agg_row_bf(const uint4* __restrict__ h4,
                                           const unsigned* __restrict__ se,
                                           int lane, int e0, int e1, float* acc) {
    float b0[8], b1[8], b2[8];
    #pragma unroll
    for (int j = 0; j < 8; ++j) { b0[j] = 0.f; b1[j] = 0.f; b2[j] = 0.f; }
    int p = e0;
    for (; p + 4 <= e1; p += 4) {
        unsigned u0 = se[p], u1 = se[p + 1], u2 = se[p + 2], u3 = se[p + 3];
        uint4 v0 = h4[(long long)(u0 & 0xFFFFu) * G + lane];
        uint4 v1 = h4[(long long)(u1 & 0xFFFFu) * G + lane];
        uint4 v2 = h4[(long long)(u2 & 0xFFFFu) * G + lane];
        uint4 v3 = h4[(long long)(u3 & 0xFFFFu) * G + lane];
        bfacc8(acc, bfhi(u0), v0);
        bfacc8(b0,  bfhi(u1), v1);
        bfacc8(b1,  bfhi(u2), v2);
        bfacc8(b2,  bfhi(u3), v3);
    }
    for (; p < e1; ++p) {
        unsigned u = se[p];
        uint4 v = h4[(long long)(u & 0xFFFFu) * G + lane];
        bfacc8(acc, bfhi(u), v);
    }
    #pragma unroll
    for (int j = 0; j < 8; ++j) acc[j] += (b0[j] + b1[j]) + b2[j];
}

// ====== standalone aggregation (layer 1, bf16 h): out = agg(h)+bias,relu ======

template<int F, bool BRELU>
__global__ void k_agg_bf(const unsigned* __restrict__ h, const int* __restrict__ rowptr,
                         const unsigned* __restrict__ se, const float* __restrict__ selfc,
                         const float* __restrict__ bias, unsigned* __restrict__ out, int n) {
    constexpr int G = F / 8;             // uint4 (8 bf16) per row
    constexpr int NPB = 256 / G;
    int gid = blockIdx.x * NPB + threadIdx.x / G;
    int lane = threadIdx.x & (G - 1);
    if (gid >= n) return;
    const uint4* h4 = (const uint4*)h;
    float acc[8];
    #pragma unroll
    for (int j = 0; j < 8; ++j) acc[j] = 0.f;
    uint4 sv = h4[(long long)gid * G + lane];
    bfacc8(acc, selfc[gid], sv);
    agg_row_bf<G>(h4, se, lane, rowptr[gid], rowptr[gid + 1], acc);
    if (BRELU) {
        float4 bv0 = ((const float4*)bias)[lane * 2];
        float4 bv1 = ((const float4*)bias)[lane * 2 + 1];
        acc[0] = fmaxf(acc[0] + bv0.x, 0.f); acc[1] = fmaxf(acc[1] + bv0.y, 0.f);
        acc[2] = fmaxf(acc[2] + bv0.z, 0.f); acc[3] = fmaxf(acc[3] + bv0.w, 0.f);
        acc[4] = fmaxf(acc[4] + bv1.x, 0.f); acc[5] = fmaxf(acc[5] + bv1.y, 0.f);
        acc[6] = fmaxf(acc[6] + bv1.z, 0.f); acc[7] = fmaxf(acc[7] + bv1.w, 0.f);
    }
    uint4 o;
    o.x = bfpack2(acc[0], acc[1]); o.y = bfpack2(acc[2], acc[3]);
    o.z = bfpack2(acc[4], acc[5]); o.w = bfpack2(acc[6], acc[7]);
    ((uint4*)out)[(long long)gid * G + lane] = o;
}

// ====== fused aggregate + dense (bf16 h in / bf16 out, fp32 compute) ======

template<int FAGG, int FOUT, int ROWS, bool RELU>
__global__ __launch_bounds__(256) void k_aggemm_bf(const unsigned* __restrict__ h,
                                                   const int* __restrict__ rowptr,
                                                   const unsigned* __restrict__ se,
                                                   const float* __restrict__ selfc,
                                                   const float* __restrict__ W,
                                                   const float* __restrict__ b,
                                                   unsigned* __restrict__ out, int n) {
    constexpr int G    = FAGG / 8;    // uint4 lanes per node
    constexpr int NPP  = 256 / G;     // nodes per agg pass
    constexpr int PASS = ROWS / NPP;
    constexpr int SA   = ROWS + 4;    // LDS row stride
    constexpr int TC   = FOUT / 4;    // thread-cols in gemm phase
    constexpr int TR   = 256 / TC;
    constexpr int R    = ROWS / TR;   // rows per thread

    __shared__ float  hT[FAGG * SA];
    __shared__ float4 bl[TC];

    int tid = threadIdx.x;
    int rowbase = blockIdx.x * ROWS;
    const float4* Wf4 = (const float4*)W;

    if (tid < TC) bl[tid] = ((const float4*)b)[tid];

    // ---- phase 1: aggregate ROWS rows into hT (transposed, fp32) ----
    const uint4* h4 = (const uint4*)h;
    int lane = tid & (G - 1);
    int sub  = tid / G;
    #pragma unroll
    for (int ps = 0; ps < PASS; ++ps) {
        int lrow = ps * NPP + sub;
        int gid = rowbase + lrow;
        int gidc = (gid < n) ? gid : (n - 1);
        float acc[8];
        #pragma unroll
        for (int j = 0; j < 8; ++j) acc[j] = 0.f;
        uint4 sv = h4[(long long)gidc * G + lane];
        bfacc8(acc, selfc[gidc], sv);
        agg_row_bf<G>(h4, se, lane, rowptr[gidc], rowptr[gidc + 1], acc);
        #pragma unroll
        for (int j = 0; j < 8; ++j)
            hT[(8 * lane + j) * SA + lrow] = acc[j];
    }
    __syncthreads();

    // ---- phase 2: gemm (fp32 from LDS, W from global L1/L2) ----
    int tc = tid % TC;
    int r0 = (tid / TC) * R;

    float4 acc[R];
    float4 binit = bl[tc];
    #pragma unroll
    for (int r = 0; r < R; ++r) acc[r] = binit;

    #pragma unroll 4
    for (int fi = 0; fi < FAGG; ++fi) {
        float4 wv = __ldg(&Wf4[fi * TC + tc]);
        float a[R];
        if constexpr (R >= 4) {
            #pragma unroll
            for (int rb = 0; rb < R / 4; ++rb) {
                float4 t = *(const float4*)&hT[fi * SA + r0 + 4 * rb];
                a[4 * rb + 0] = t.x; a[4 * rb + 1] = t.y;
                a[4 * rb + 2] = t.z; a[4 * rb + 3] = t.w;
            }
        } else if constexpr (R == 2) {
            float2 t = *(const float2*)&hT[fi * SA + r0];
            a[0] = t.x; a[1] = t.y;
        } else {
            a[0] = hT[fi * SA + r0];
        }
        #pragma unroll
        for (int r = 0; r < R; ++r) {
            acc[r].x += a[r] * wv.x; acc[r].y += a[r] * wv.y;
            acc[r].z += a[r] * wv.z; acc[r].w += a[r] * wv.w;
        }
    }

    #pragma unroll
    for (int r = 0; r < R; ++r) {
        int row = rowbase + r0 + r;
        if (row < n) {
            float4 v = acc[r];
            if (RELU) {
                v.x = fmaxf(v.x, 0.f); v.y = fmaxf(v.y, 0.f);
                v.z = fmaxf(v.z, 0.f); v.w = fmaxf(v.w, 0.f);
            }
            uint2 o;
            o.x = bfpack2(v.x, v.y); o.y = bfpack2(v.z, v.w);
            ((uint2*)out)[(long long)row * (FOUT / 4) + tc] = o;
        }
    }
}

// ============ global add pool + relu (two-phase, bf16 h, batch sorted) ============

__global__ __launch_bounds__(64) void k_pool1(const unsigned* __restrict__ h,
                                              const int* __restrict__ batch,
                                              float* __restrict__ part, int n) {
    int g = blockIdx.x / PSLICE;
    int s = blockIdx.x % PSLICE;
    int lo = 0, hi = n;
    while (lo < hi) { int m = (lo + hi) >> 1; if (batch[m] < g) lo = m + 1; else hi = m; }
    int start = lo;
    hi = n;
    while (lo < hi) { int m = (lo + hi) >> 1; if (batch[m] < g + 1) lo = m + 1; else hi = m; }
    int end = lo;
    int len = end - start;
    int a = start + (int)((long long)len * s / PSLICE);
    int bnd = start + (int)((long long)len * (s + 1) / PSLICE);
    int t = threadIdx.x;                 // covers features 2t, 2t+1 (row = 64 uints)
    float a0 = 0.f, a1 = 0.f, b0 = 0.f, b1 = 0.f;
    int i = a;
    for (; i + 2 <= bnd; i += 2) {
        unsigned u0 = h[(long long)(i + 0) * 64 + t];
        unsigned u1 = h[(long long)(i + 1) * 64 + t];
        a0 += bflo(u0); a1 += bfhi(u0);
        b0 += bflo(u1); b1 += bfhi(u1);
    }
    if (i < bnd) {
        unsigned u0 = h[(long long)i * 64 + t];
        a0 += bflo(u0); a1 += bfhi(u0);
    }
    part[(long long)blockIdx.x * 128 + 2 * t]     = a0 + b0;
    part[(long long)blockIdx.x * 128 + 2 * t + 1] = a1 + b1;
}

__global__ __launch_bounds__(128) void k_pool2(const float* __restrict__ part,
                                               float* __restrict__ out) {
    int g = blockIdx.x;
    int f = threadIdx.x;
    float acc = 0.f;
    #pragma unroll
    for (int s = 0; s < PSLICE; ++s)
        acc += part[(long long)(g * PSLICE + s) * 128 + f];
    out[g * 128 + f] = fmaxf(acc, 0.0f);
}

// ================= launch =================

static inline int cdiv(long long a, int b) { return (int)((a + b - 1) / b); }

extern "C" void kernel_launch(void* const* d_in, const int* in_sizes, int n_in,
                              void* d_out, int out_size, void* d_ws, size_t ws_size,
                              hipStream_t stream) {
    const float* x    = (const float*)d_in[0];
    const int*   src  = (const int*)d_in[1];
    const int*   dst  = src + NE;
    const float* ew   = (const float*)d_in[2];
    const int*   batch= (const int*)d_in[3];
    const float* W1 = (const float*)d_in[4];  const float* b1 = (const float*)d_in[5];
    const float* W2 = (const float*)d_in[6];  const float* b2 = (const float*)d_in[7];
    const float* W3 = (const float*)d_in[8];  const float* b3 = (const float*)d_in[9];
    const float* W4 = (const float*)d_in[10]; const float* b4 = (const float*)d_in[11];
    const float* W5 = (const float*)d_in[12]; const float* b5 = (const float*)d_in[13];
    float* out = (float*)d_out;

    // ---- workspace layout (floats) ----
    float* ws = (float*)d_ws;
    int*      rowptr = (int*)ws;                       // [50004] ints
    unsigned* sedge  = (unsigned*)(ws + 50004);        // [NE] uints (region reserves 2*NE)
    float*    selfc  = ws + 50004 + 2 * (size_t)NE;    // [NN]
    float*    dinv   = selfc + NN;                     // [NN]
    float*    bufA   = dinv + NN;                      // [NN*64] floats
    float*    bufB   = bufA + (size_t)NN * 64;         // [NN*128] floats
    unsigned* hA  = (unsigned*)bufA;                   // bf16 h buffers
    unsigned* hB  = (unsigned*)bufB;
    int2*     tmp = (int2*)bufB;                       // NE int2 (dead before hB written)
    // dedicated CSR/pool scratch AFTER bufB (no overlay with hA — fat kernel runs
    // kA1 and gemm1 concurrently):
    int*   pbb        = (int*)(bufB + (size_t)NN * 128);   // NBLK*NBUK ints
    int*   bucketCnt  = pbb + NBLK * NBUK;                 // NBUK
    int*   bucketBase = bucketCnt + NBUK;                  // NBUK+1
    float* part       = (float*)(bucketBase + NBUK + 1);   // NG*PSLICE*128 fp32

    const int T = 256;

    // ---- fat kernel: kA1 histogram ∥ layer-1 GEMM (independent) ----
    k_fat1<<<NBLK + cdiv(NN, 64), T, 0, stream>>>(dst, pbb, x, W1, hA, NN);

    // ---- CSR build (coalesced, parallel atomic-free offsets) ----
    k_pbbscan<<<cdiv(NBUK, 4), T, 0, stream>>>(pbb, bucketCnt);
    k_bscan<<<1, T, 0, stream>>>(bucketCnt, bucketBase, rowptr);
    kA2<<<NBLK, T, 0, stream>>>(src, dst, ew, bucketBase, pbb, tmp);
    kB<<<NBUK, T, 0, stream>>>(tmp, bucketBase, rowptr, dinv, selfc, sedge);
    k_coef<<<cdiv(NN, T), T, 0, stream>>>(rowptr, dinv, sedge);

    // ---- layer 1 aggregate (+bias+relu) ----
    k_agg_bf<16, true><<<cdiv(NN, 128), T, 0, stream>>>(hA, rowptr, sedge, selfc, b1, hB, NN);

    // ---- layers 2-5: fused aggregate + dense (bf16 h, fp32 compute) ----
    k_aggemm_bf<16, 32, 128, true ><<<cdiv(NN, 128), T, 0, stream>>>(hB, rowptr, sedge, selfc, W2, b2, hA, NN);
    k_aggemm_bf<32, 64,  64, true ><<<cdiv(NN, 64),  T, 0, stream>>>(hA, rowptr, sedge, selfc, W3, b3, hB, NN);
    k_aggemm_bf<64, 64,  64, true ><<<cdiv(NN, 64),  T, 0, stream>>>(hB, rowptr, sedge, selfc, W4, b4, hA, NN);
    k_aggemm_bf<64, 128, 64, false><<<cdiv(NN, 64),  T, 0, stream>>>(hA, rowptr, sedge, selfc, W5, b5, hB, NN);

    // ---- global add pool + relu (two-phase) ----
    k_pool1<<<NG * PSLICE, 64, 0, stream>>>(hB, batch, part, NN);
    k_pool2<<<NG, 128, 0, stream>>>(part, out);
}